// Round 3
// baseline (280.536 us; speedup 1.0000x reference)
//
#include <hip/hip_runtime.h>

// Dice metric: input (B=4, C=5, D=H=W=128) fp32, target (B,128^3) int32.
// out[0] = mean over (B, classes 1..4) of (2*inter + eps)/(pred_c + tgt_c + eps)
// where pred = argmax_c input.

static constexpr int   kB   = 4;
static constexpr int   kC   = 5;
static constexpr int   kN   = 128 * 128 * 128;      // voxels per batch
static constexpr float kEPS = 1e-5f;

static constexpr int TPB = 256;                     // threads per block
static constexpr int VPT = 2;                       // float4 groups per thread (8 voxels)
static constexpr int GPB = TPB * VPT;               // 512 float4 groups / block
static constexpr int BLOCKS_PER_BATCH = (kN / 4) / GPB;   // 1024
static constexpr int kNumCnt = kB * 12;             // [b][group(P,T,I)][class-1]

__device__ __forceinline__ int argmax5(float v0, float v1, float v2, float v3, float v4) {
    int bi = 0; float bv = v0;
    if (v1 > bv) { bv = v1; bi = 1; }
    if (v2 > bv) { bv = v2; bi = 2; }
    if (v3 > bv) { bv = v3; bi = 3; }
    if (v4 > bv) { bv = v4; bi = 4; }
    return bi;   // first-max semantics == jnp.argmax
}

// Byte-packed counters: byte k of pack = count for class k+1. Max 8 voxels/thread.
__device__ __forceinline__ void acc1(int p, int t,
                                     unsigned& P, unsigned& T, unsigned& I) {
    unsigned pm = p ? (1u << ((p - 1) << 3)) : 0u;
    unsigned tm = t ? (1u << ((t - 1) << 3)) : 0u;
    P += pm;
    T += tm;
    I += (p == t) ? pm : 0u;      // p==t==0 -> pm==0, background excluded for free
}

__global__ __launch_bounds__(TPB) void dice_count_kernel(
        const float* __restrict__ in, const int* __restrict__ tgt,
        unsigned* __restrict__ cnt)
{
    const int b   = blockIdx.x >> 10;       // / BLOCKS_PER_BATCH (1024)
    const int blk = blockIdx.x & 1023;
    const float* inb = in  + (size_t)b * kC * kN;
    const int*   tb  = tgt + (size_t)b * kN;

    const float4* c0 = (const float4*)(inb + 0 * (size_t)kN);
    const float4* c1 = (const float4*)(inb + 1 * (size_t)kN);
    const float4* c2 = (const float4*)(inb + 2 * (size_t)kN);
    const float4* c3 = (const float4*)(inb + 3 * (size_t)kN);
    const float4* c4 = (const float4*)(inb + 4 * (size_t)kN);
    const int4*   tp = (const int4*)tb;

    const int base = blk * GPB + threadIdx.x;

    // Load everything first (independent registers -> max loads in flight),
    // small enough footprint (~12 x 16B) to keep occupancy near full.
    float4 v[VPT][5];
    int4   tv[VPT];
#pragma unroll
    for (int i = 0; i < VPT; ++i) {
        const int n4 = base + i * TPB;
        v[i][0] = c0[n4];
        v[i][1] = c1[n4];
        v[i][2] = c2[n4];
        v[i][3] = c3[n4];
        v[i][4] = c4[n4];
        tv[i]   = tp[n4];
    }

    unsigned P = 0, T = 0, I = 0;
#pragma unroll
    for (int i = 0; i < VPT; ++i) {
        acc1(argmax5(v[i][0].x, v[i][1].x, v[i][2].x, v[i][3].x, v[i][4].x), tv[i].x, P, T, I);
        acc1(argmax5(v[i][0].y, v[i][1].y, v[i][2].y, v[i][3].y, v[i][4].y), tv[i].y, P, T, I);
        acc1(argmax5(v[i][0].z, v[i][1].z, v[i][2].z, v[i][3].z, v[i][4].z), tv[i].z, P, T, I);
        acc1(argmax5(v[i][0].w, v[i][1].w, v[i][2].w, v[i][3].w, v[i][4].w), tv[i].w, P, T, I);
    }

    // Widen bytes -> halfwords so a 64-lane sum can't overflow (8*64=512 < 65536).
    // r[2g+0]: classes 1(lo16) & 3(hi16); r[2g+1]: classes 2(lo16) & 4(hi16).
    unsigned r[6];
    r[0] = P & 0x00FF00FFu;  r[1] = (P >> 8) & 0x00FF00FFu;
    r[2] = T & 0x00FF00FFu;  r[3] = (T >> 8) & 0x00FF00FFu;
    r[4] = I & 0x00FF00FFu;  r[5] = (I >> 8) & 0x00FF00FFu;

#pragma unroll
    for (int k = 0; k < 6; ++k) {
#pragma unroll
        for (int off = 32; off > 0; off >>= 1) {
            r[k] += (unsigned)__shfl_down((int)r[k], off, 64);
        }
    }

    __shared__ unsigned sred[4][6];         // 4 waves per block
    const int wave = threadIdx.x >> 6;
    if ((threadIdx.x & 63) == 0) {
#pragma unroll
        for (int k = 0; k < 6; ++k) sred[wave][k] = r[k];
    }
    __syncthreads();

    // One thread per packed pair -> 12 atomicAdds per block total.
    if (threadIdx.x < 6) {
        const int j = threadIdx.x;
        unsigned s = sred[0][j] + sred[1][j] + sred[2][j] + sred[3][j];  // <= 2048/field
        const int g   = j >> 1;             // 0=pred,1=tgt,2=inter
        const int kLo = j & 1;              // class-1 index: 0 or 1
        unsigned* dst = cnt + b * 12 + g * 4;
        atomicAdd(&dst[kLo],     s & 0xFFFFu);
        atomicAdd(&dst[kLo + 2], s >> 16);
    }
}

__global__ void dice_final_kernel(const unsigned* __restrict__ cnt,
                                  float* __restrict__ out)
{
    if (threadIdx.x == 0 && blockIdx.x == 0) {
        float s = 0.0f;
#pragma unroll
        for (int b = 0; b < kB; ++b) {
#pragma unroll
            for (int k = 0; k < 4; ++k) {
                float pr = (float)cnt[b * 12 + 0 * 4 + k];
                float tg = (float)cnt[b * 12 + 1 * 4 + k];
                float it = (float)cnt[b * 12 + 2 * 4 + k];
                s += (2.0f * it + kEPS) / (pr + tg + kEPS);
            }
        }
        out[0] = s * (1.0f / 16.0f);
    }
}

extern "C" void kernel_launch(void* const* d_in, const int* in_sizes, int n_in,
                              void* d_out, int out_size, void* d_ws, size_t ws_size,
                              hipStream_t stream) {
    const float* in  = (const float*)d_in[0];
    const int*   tgt = (const int*)d_in[1];
    float*       out = (float*)d_out;
    unsigned*    cnt = (unsigned*)d_ws;

    // d_ws is poisoned to 0xAA before every launch -> zero the counters.
    hipMemsetAsync(cnt, 0, kNumCnt * sizeof(unsigned), stream);

    dice_count_kernel<<<dim3(kB * BLOCKS_PER_BATCH), dim3(TPB), 0, stream>>>(in, tgt, cnt);
    dice_final_kernel<<<1, 64, 0, stream>>>(cnt, out);
}

// Round 4
// 254.862 us; speedup vs baseline: 1.1007x; 1.1007x over previous
//
#include <hip/hip_runtime.h>

// Dice metric: input (B=4, C=5, D=H=W=128) fp32, target (B,128^3) int32.
// out[0] = mean over (B, classes 1..4) of (2*inter + eps)/(pred_c + tgt_c + eps)
// where pred = argmax_c input.
//
// Two-stage, ZERO atomics (R3 post-mortem: 49k same-line atomicAdds serialized
// at ~5cyc each == the entire 102us kernel duration). Stage 1 writes per-block
// partial counts with plain stores; stage 2 (1 block) reduces 2048x12 words.

static constexpr int   kB   = 4;
static constexpr int   kC   = 5;
static constexpr int   kN   = 128 * 128 * 128;      // voxels per batch
static constexpr float kEPS = 1e-5f;

static constexpr int TPB   = 256;                   // threads per block
static constexpr int ITERS = 4;                     // float4 groups per thread
static constexpr int GPB   = TPB * ITERS;           // 1024 groups per block
static constexpr int BPB   = (kN / 4) / GPB;        // 512 blocks per batch
static constexpr int NBLK  = kB * BPB;              // 2048 blocks total

__device__ __forceinline__ int argmax5(float v0, float v1, float v2, float v3, float v4) {
    int bi = 0; float bv = v0;
    if (v1 > bv) { bv = v1; bi = 1; }
    if (v2 > bv) { bv = v2; bi = 2; }
    if (v3 > bv) { bv = v3; bi = 3; }
    if (v4 > bv) { bv = v4; bi = 4; }
    return bi;   // first-max semantics == jnp.argmax
}

// Byte-packed counters: byte k = count for class k+1. 16 voxels/thread max -> safe.
__device__ __forceinline__ void acc1(int p, int t,
                                     unsigned& P, unsigned& T, unsigned& I) {
    unsigned pm = p ? (1u << ((p - 1) << 3)) : 0u;
    unsigned tm = t ? (1u << ((t - 1) << 3)) : 0u;
    P += pm;
    T += tm;
    I += (p == t) ? pm : 0u;      // p==t==0 -> pm==0, background excluded for free
}

__global__ __launch_bounds__(TPB) void dice_count_kernel(
        const float* __restrict__ in, const int* __restrict__ tgt,
        unsigned* __restrict__ partial)
{
    const int bg  = blockIdx.x;
    const int b   = bg >> 9;                // / BPB (512)
    const int blk = bg & 511;
    const float* inb = in  + (size_t)b * kC * kN;
    const int*   tb  = tgt + (size_t)b * kN;

    const float4* c0 = (const float4*)(inb + 0 * (size_t)kN);
    const float4* c1 = (const float4*)(inb + 1 * (size_t)kN);
    const float4* c2 = (const float4*)(inb + 2 * (size_t)kN);
    const float4* c3 = (const float4*)(inb + 3 * (size_t)kN);
    const float4* c4 = (const float4*)(inb + 4 * (size_t)kN);
    const int4*   tp = (const int4*)tb;

    const int base = blk * GPB + threadIdx.x;

    unsigned P = 0, T = 0, I = 0;
    // Loop (not straight-line): lets the scheduler pipeline iteration i+1's
    // loads over iteration i's compute -- the m13 copy-ubench pattern.
#pragma unroll 2
    for (int i = 0; i < ITERS; ++i) {
        const int n4 = base + i * TPB;
        float4 v0 = c0[n4];
        float4 v1 = c1[n4];
        float4 v2 = c2[n4];
        float4 v3 = c3[n4];
        float4 v4 = c4[n4];
        int4   t4 = tp[n4];
        acc1(argmax5(v0.x, v1.x, v2.x, v3.x, v4.x), t4.x, P, T, I);
        acc1(argmax5(v0.y, v1.y, v2.y, v3.y, v4.y), t4.y, P, T, I);
        acc1(argmax5(v0.z, v1.z, v2.z, v3.z, v4.z), t4.z, P, T, I);
        acc1(argmax5(v0.w, v1.w, v2.w, v3.w, v4.w), t4.w, P, T, I);
    }

    // Widen bytes -> halfwords so a 64-lane sum can't overflow (16*64=1024 < 65536).
    // r[2g+0]: classes 1(lo16) & 3(hi16); r[2g+1]: classes 2(lo16) & 4(hi16).
    unsigned r[6];
    r[0] = P & 0x00FF00FFu;  r[1] = (P >> 8) & 0x00FF00FFu;
    r[2] = T & 0x00FF00FFu;  r[3] = (T >> 8) & 0x00FF00FFu;
    r[4] = I & 0x00FF00FFu;  r[5] = (I >> 8) & 0x00FF00FFu;

#pragma unroll
    for (int k = 0; k < 6; ++k) {
#pragma unroll
        for (int off = 32; off > 0; off >>= 1) {
            r[k] += (unsigned)__shfl_down((int)r[k], off, 64);
        }
    }

    __shared__ unsigned sred[4][6];         // 4 waves per block
    const int wave = threadIdx.x >> 6;
    if ((threadIdx.x & 63) == 0) {
#pragma unroll
        for (int k = 0; k < 6; ++k) sred[wave][k] = r[k];
    }
    __syncthreads();

    // Plain stores of the 12 per-block partials (NO atomics).
    // Layout: partial[bg*12 + g*4 + k], g 0=pred,1=tgt,2=inter, k=class-1.
    if (threadIdx.x < 6) {
        const int j = threadIdx.x;
        unsigned s = sred[0][j] + sred[1][j] + sred[2][j] + sred[3][j];  // <= 4096/field
        const int g   = j >> 1;
        const int kLo = j & 1;
        unsigned* dst = partial + bg * 12 + g * 4;
        dst[kLo]     = s & 0xFFFFu;
        dst[kLo + 2] = s >> 16;
    }
}

__global__ __launch_bounds__(256) void dice_reduce_kernel(
        const unsigned* __restrict__ partial, float* __restrict__ out)
{
    // 2048 blocks x 12 words. Thread t sums 8 chunks of 256; chunk c covers
    // bg in [c*256, c*256+256) which lies entirely in batch b = c>>1.
    unsigned acc[4][12];
#pragma unroll
    for (int b = 0; b < 4; ++b)
#pragma unroll
        for (int j = 0; j < 12; ++j) acc[b][j] = 0;

#pragma unroll
    for (int c = 0; c < 8; ++c) {
        const int b  = c >> 1;
        const int bg = c * 256 + threadIdx.x;
        const uint4* p = (const uint4*)(partial + bg * 12);   // 48B, 16B-aligned
        uint4 x = p[0], y = p[1], z = p[2];
        acc[b][0] += x.x; acc[b][1]  += x.y; acc[b][2]  += x.z; acc[b][3]  += x.w;
        acc[b][4] += y.x; acc[b][5]  += y.y; acc[b][6]  += y.z; acc[b][7]  += y.w;
        acc[b][8] += z.x; acc[b][9]  += z.y; acc[b][10] += z.z; acc[b][11] += z.w;
    }

#pragma unroll
    for (int b = 0; b < 4; ++b)
#pragma unroll
        for (int j = 0; j < 12; ++j)
#pragma unroll
            for (int off = 32; off > 0; off >>= 1)
                acc[b][j] += (unsigned)__shfl_down((int)acc[b][j], off, 64);

    __shared__ unsigned part[4][48];
    const int wave = threadIdx.x >> 6;
    if ((threadIdx.x & 63) == 0) {
#pragma unroll
        for (int b = 0; b < 4; ++b)
#pragma unroll
            for (int j = 0; j < 12; ++j) part[wave][b * 12 + j] = acc[b][j];
    }
    __syncthreads();

    __shared__ unsigned tot[48];
    if (threadIdx.x < 48) {
        const int t = threadIdx.x;
        tot[t] = part[0][t] + part[1][t] + part[2][t] + part[3][t];
    }
    __syncthreads();

    if (threadIdx.x < 16) {
        const int b = threadIdx.x >> 2;
        const int k = threadIdx.x & 3;
        float pr = (float)tot[b * 12 + 0 + k];
        float tg = (float)tot[b * 12 + 4 + k];
        float it = (float)tot[b * 12 + 8 + k];
        float d = (2.0f * it + kEPS) / (pr + tg + kEPS);
#pragma unroll
        for (int off = 8; off > 0; off >>= 1) d += __shfl_down(d, off, 16);
        if (threadIdx.x == 0) out[0] = d * (1.0f / 16.0f);
    }
}

extern "C" void kernel_launch(void* const* d_in, const int* in_sizes, int n_in,
                              void* d_out, int out_size, void* d_ws, size_t ws_size,
                              hipStream_t stream) {
    const float* in  = (const float*)d_in[0];
    const int*   tgt = (const int*)d_in[1];
    float*       out = (float*)d_out;
    unsigned*    partial = (unsigned*)d_ws;

    // Every partial slot is written unconditionally by dice_count_kernel,
    // so no memset of d_ws is needed despite the 0xAA poison.
    dice_count_kernel<<<dim3(NBLK), dim3(TPB), 0, stream>>>(in, tgt, partial);
    dice_reduce_kernel<<<dim3(1), dim3(256), 0, stream>>>(partial, out);
}